// Round 11
// baseline (1299.555 us; speedup 1.0000x reference)
//
#include <hip/hip_runtime.h>

// GPUHungarianMatcher R18 — exact replication of the reference's degenerate
// "_lsa" (minv reset every inner iteration => chain-Dijkstra). One block per
// batch; R18 = R15's validated structure at NT=512 (8 waves, KPT=4).
//
// Rationale (R10-R17 ledger): the 4-wave spine is latency-bound — ~280cy
// issue vs ~850cy step; stalls are overlapping dependency gaps no single
// fix closes (R12/R14/R15 all ±3%). R16 proved single-stream dual-chain
// interleave gets ZERO overlap (compiler won't interleave across basic
// blocks). But HW co-issues separate WAVES on one SIMD (m114). R15 has
// 1 wave/SIMD => stalls are dead cycles. R18 puts 2 waves/SIMD working on
// the SAME chain: per-SIMD scan issue is unchanged (512 cols/SIMD either
// way), but wave X's DPP/mailbox/f64-tree stalls are filled by wave Y's
// issue. Costs accepted: per-wave redundant combine work doubles per SIMD
// (absorbed into stalls), 8-wide tournament (depth 3), 8-wave barrier.
//
// Exactness (absmax-0 lineage R2-R17):
//  * column mapping: thread t owns c = (t&255) + (4*(t>>8)+k)*256, k=0..3
//    (j = c+1). Argmin tie-break is lexicographic (key, true column index)
//    => mapping-independent np.argmin first-occurrence.
//  * softmax: stats via the EXACT R2 tree on threads 0-255 with the OLD
//    mapping (wave-uniform guard; waves 4-7 skip), smax/ssum broadcast;
//    then EVERY thread recomputes np_ for its 4 columns:
//    -(expf(xs_c - smax)/ssum) — deterministic => bitwise-equal per column.
//  * scan cur = ((double)cf - ui0) - vreg[k], f32 +inf poison for used
//    columns (per-wave all-used impossible: used <= 255 < 256 cols/wave).
//  * 8-wide pairwise tournament, left wins ties at every level == leftmost
//    minimum == left-to-right scan; cd folded along the same selectors in
//    the u32 domain.
//  * u update: single add of prefix-difference (recU); v update: vdelta
//    scatter (bitwise-identical values); no barrier E; S==1 fast path
//    (owner writes colDat/p; unew = 0+(D-0) = D bitwise); GLOBAL parity.
//  * colDat UNPADDED (R17 lesson: e mod 8 = (tid+1) mod 8 is bk-independent
//    => uniform bank groups; padding made it data-dependent and WORSE).

constexpr int B = 8;
constexpr int Q = 2048;        // columns (queries)
constexpr int T = 256;         // rows (targets)
constexpr int NT = 512;        // threads per block (8 waves, 2 per SIMD)
constexpr int KPT = 4;         // 4 columns per thread
constexpr int NW = NT / 64;    // 8 waves

struct __align__(16) CD { double u; float tx, ty; };   // one ds_read_b128

__device__ __forceinline__ unsigned wave_min_u32_dpp(unsigned a) {
  // full-wave u32 min: row_shr 1,2,4,8 then row_bcast15, row_bcast31;
  // invalid source lanes keep old (bound_ctrl=false, masks 0xf) = identity.
  int v = (int)a, t;
  t = __builtin_amdgcn_update_dpp(v, v, 0x111, 0xf, 0xf, false);
  v = ((unsigned)t < (unsigned)v) ? t : v;
  t = __builtin_amdgcn_update_dpp(v, v, 0x112, 0xf, 0xf, false);
  v = ((unsigned)t < (unsigned)v) ? t : v;
  t = __builtin_amdgcn_update_dpp(v, v, 0x114, 0xf, 0xf, false);
  v = ((unsigned)t < (unsigned)v) ? t : v;
  t = __builtin_amdgcn_update_dpp(v, v, 0x118, 0xf, 0xf, false);
  v = ((unsigned)t < (unsigned)v) ? t : v;
  t = __builtin_amdgcn_update_dpp(v, v, 0x142, 0xf, 0xf, false);
  v = ((unsigned)t < (unsigned)v) ? t : v;
  t = __builtin_amdgcn_update_dpp(v, v, 0x143, 0xf, 0xf, false);
  v = ((unsigned)t < (unsigned)v) ? t : v;
  return (unsigned)__builtin_amdgcn_readlane(v, 63);   // lane 63 = global min
}

__launch_bounds__(NT, 1)
__global__ void hungarian_r18(const float* __restrict__ outs,
                              const float* __restrict__ tgts,
                              int* __restrict__ out) {
  const int b = blockIdx.x;
  const int tid = threadIdx.x;
  const int lane = tid & 63;
  const int wv = tid >> 6;          // 0..7
  const int half = tid >> 8;        // 0 or 1
  const int base = tid & 255;

  __shared__ CD colDat[Q + 1];      // UNPADDED (R17 lesson); tx=-1.0f = free
  __shared__ float2 rowTgt[T + 1];  // read-only after init
  __shared__ short p[Q + 1];        // p[j]: row matched to col j, 0 free
  __shared__ uint4 pk2[2][NW][2];   // mailbox (GLOBAL parity):
                                    //   [.][w][0] = {khi, klo, bidx, 0}
                                    //   [.][w][1] = {u_lo, u_hi, tx, ty}
  __shared__ double vdelta[Q];      // v-delta scatter; 0.0 = no update
  __shared__ int ansArr[T];
  __shared__ double s_rv[4];        // R2-tree partials (256-thread mapping)
  __shared__ float sh_f;

  const size_t qbase = (size_t)b * Q;
  const size_t tbase = (size_t)b * T;

  // ---- stage MY 4 columns (c = base + (4*half+k)*256) ----
  float xsm[KPT], qx[KPT], qy[KPT];
#pragma unroll
  for (int k = 0; k < KPT; ++k) {
    const int c = base + ((half * 4 + k) << 8);
    const size_t o = (qbase + c) * 3;
    xsm[k] = outs[o];
    qx[k] = outs[o + 1];
    qy[k] = outs[o + 2];
  }
  // stats inputs: the OLD 256-thread mapping (threads 0-255, 8 cols each)
  float xs8[8];
  if (tid < 256) {
#pragma unroll
    for (int k = 0; k < 8; ++k) xs8[k] = outs[(qbase + base + (k << 8)) * 3];
  }
  if (tid < 256) {
    const size_t o = (tbase + tid) * 3;   // one target per thread
    rowTgt[tid + 1] = make_float2(tgts[o + 1], tgts[o + 2]);
    if (tid == 0) rowTgt[0] = make_float2(0.f, 0.f);
  }

  // ---- softmax stats: EXACT R2 tree on threads 0-255 (wave-uniform guard) --
  if (tid < 256) {
    float lmax = xs8[0];
#pragma unroll
    for (int k = 1; k < 8; ++k) lmax = fmaxf(lmax, xs8[k]);
    for (int off = 32; off > 0; off >>= 1) lmax = fmaxf(lmax, __shfl_down(lmax, off));
    if ((tid & 63) == 0) s_rv[tid >> 6] = (double)lmax;
  }
  __syncthreads();
  if (tid == 0) {
    float m2 = (float)s_rv[0];
    for (int w = 1; w < 4; ++w) m2 = fmaxf(m2, (float)s_rv[w]);
    sh_f = m2;
  }
  __syncthreads();
  const float smax = sh_f;
  if (tid < 256) {
    float lsum = 0.f;
#pragma unroll
    for (int k = 0; k < 8; ++k) lsum += expf(xs8[k] - smax);
    for (int off = 32; off > 0; off >>= 1) lsum += __shfl_down(lsum, off);
    if ((tid & 63) == 0) s_rv[tid >> 6] = (double)lsum;
  }
  __syncthreads();
  if (tid == 0) {
    float s2 = 0.f;
    for (int w = 0; w < 4; ++w) s2 += (float)s_rv[w];
    sh_f = s2;
  }
  __syncthreads();
  const float ssum = sh_f;
  // per-column np_ recompute: expf/div deterministic => bitwise == R2 values
  float np_[KPT];
#pragma unroll
  for (int k = 0; k < KPT; ++k) np_[k] = -(expf(xsm[k] - smax) / ssum);

  // ---- init state ----
  for (int j = tid; j <= Q; j += NT) {
    p[j] = 0;
    CD c0; c0.u = 0.0; c0.tx = -1.0f; c0.ty = 0.0f;   // all columns free
    colDat[j] = c0;
  }
  double vreg[KPT];   // v for my 4 columns (static indices only)
#pragma unroll
  for (int k = 0; k < KPT; ++k) {
    vreg[k] = 0.0;
    vdelta[base + ((half * 4 + k) << 8)] = 0.0;
  }
  __syncthreads();

  const float FINF = __int_as_float(0x7f800000);   // +inf poison
  float2 nxtT = rowTgt[1];                         // prefetch row 1's target
  int par = 0;                                     // GLOBAL mailbox parity

  // ---- main loop over rows ----
  for (int i = 1; i <= T; ++i) {
    unsigned usedMask = 0;
    double D = 0.0;
    int i0 = i;
    double ui0 = 0.0;                // u[i] == 0 at row i's search start
    float tX = nxtT.x, tY = nxtT.y;
    int s = 0, S;
    int j1v = 0;
    int recRow = 0, recCol = 0, recPrev = 0;   // thread t records step t
    double recU = 0.0, recD = 0.0;
    float recTX = 0.f, recTY = 0.f;

    for (;;) {
      const int cpar = par; par ^= 1;   // global parity (uniform: lockstep)

      if (tid == s) {
        recRow = i0; recU = ui0; recTX = tX; recTY = tY; recD = D; recPrev = j1v;
      }

      // scan my 4 columns
      double cv[KPT];
#pragma unroll
      for (int k = 0; k < KPT; ++k) {
        float cf = fabsf(qx[k] - tX) + fabsf(qy[k] - tY) + np_[k];
        if (usedMask & (1u << k)) cf = FINF;
        cv[k] = ((double)cf - ui0) - vreg[k];
      }
      // intra-lane argmin (fmin tree + ==-mask + ctz = first occurrence)
      const double m01 = fmin(cv[0], cv[1]), m23 = fmin(cv[2], cv[3]);
      double bval = fmin(m01, m23);
      unsigned emsk = 0;
#pragma unroll
      for (int k = 0; k < KPT; ++k) emsk |= (cv[k] == bval) ? (1u << k) : 0u;
      const int bk = (int)__builtin_ctz(emsk);
      int bidx = 1 + base + ((half * 4 + bk) << 8);   // true column index

      // pre-barrier owner-read of MY candidate's colDat (uniform banks:
      // element index mod 8 = (base+1) mod 8, independent of bk)
      const CD myCd = colDat[bidx];

      // monotone u64 bit-key (canonicalize -0 -> +0)
      bval += 0.0;
      const long long bb = __double_as_longlong(bval);
      const unsigned long long key = (unsigned long long)bb ^
          ((bb < 0) ? 0xFFFFFFFFFFFFFFFFull : 0x8000000000000000ull);
      const unsigned khi = (unsigned)(key >> 32);
      const unsigned klo = (unsigned)key;

      // wave argmin: DPP min on hi32 + ballot; exact-tie slow path
      const unsigned minhi = wave_min_u32_dpp(khi);
      const unsigned long long mask = __ballot(khi == minhi);
      int wl;
      if (__popcll(mask) == 1) {
        wl = (int)__ffsll(mask) - 1;
      } else {
        unsigned wklo = 0xffffffffu; int widx = 0x7fffffff; wl = 0;
        unsigned long long mm = mask;
        while (mm) {
          const int l = (int)__ffsll(mm) - 1; mm &= mm - 1;
          const unsigned lo2 = (unsigned)__builtin_amdgcn_readlane((int)klo, l);
          const int ix2 = __builtin_amdgcn_readlane(bidx, l);
          if (lo2 < wklo || (lo2 == wklo && ix2 < widx)) {
            wklo = lo2; widx = ix2; wl = l;
          }
        }
      }
      if (lane == wl) {
        pk2[cpar][wv][0] = make_uint4(minhi, klo, (unsigned)bidx, 0u);
        const unsigned long long cu =
            (unsigned long long)__double_as_longlong(myCd.u);
        pk2[cpar][wv][1] = make_uint4((unsigned)cu, (unsigned)(cu >> 32),
                                      __float_as_uint(myCd.tx),
                                      __float_as_uint(myCd.ty));
      }
      __syncthreads();            // the only per-step barrier

      // 8-wide tournament: left wins ties at every level == leftmost min
      unsigned long long kk[NW]; int jj[NW]; uint4 dd[NW];
#pragma unroll
      for (int w = 0; w < NW; ++w) {
        const uint4 cw = pk2[cpar][w][0];
        dd[w] = pk2[cpar][w][1];
        kk[w] = ((unsigned long long)cw.x << 32) | cw.y;
        jj[w] = (int)cw.z;
      }
      unsigned long long kA, kB, kC, kD2, kE, kF2, kW;
      int jA, jB, jC, jD2, jE, jF2, jW;
      uint4 dA, dB, dC, dD2, dE, dF2, dW;
      {
        bool w;
        w = (kk[1] < kk[0]) || (kk[1] == kk[0] && jj[1] < jj[0]);
        kA = w ? kk[1] : kk[0]; jA = w ? jj[1] : jj[0]; dA = w ? dd[1] : dd[0];
        w = (kk[3] < kk[2]) || (kk[3] == kk[2] && jj[3] < jj[2]);
        kB = w ? kk[3] : kk[2]; jB = w ? jj[3] : jj[2]; dB = w ? dd[3] : dd[2];
        w = (kk[5] < kk[4]) || (kk[5] == kk[4] && jj[5] < jj[4]);
        kC = w ? kk[5] : kk[4]; jC = w ? jj[5] : jj[4]; dC = w ? dd[5] : dd[4];
        w = (kk[7] < kk[6]) || (kk[7] == kk[6] && jj[7] < jj[6]);
        kD2 = w ? kk[7] : kk[6]; jD2 = w ? jj[7] : jj[6]; dD2 = w ? dd[7] : dd[6];
        w = (kB < kA) || (kB == kA && jB < jA);
        kE = w ? kB : kA; jE = w ? jB : jA; dE = w ? dB : dA;
        w = (kD2 < kC) || (kD2 == kC && jD2 < jC);
        kF2 = w ? kD2 : kC; jF2 = w ? jD2 : jC; dF2 = w ? dD2 : dC;
        w = (kF2 < kE) || (kF2 == kE && jF2 < jE);
        kW = w ? kF2 : kE; jW = w ? jF2 : jE; dW = w ? dF2 : dE;
      }
      const int j1 = jW;                         // selected column, 1-based
      const double cdun = __longlong_as_double(
          (long long)(((unsigned long long)dW.y << 32) | dW.x));
      const float cdtx = __uint_as_float(dW.z);
      const float cdty = __uint_as_float(dW.w);

      // invert bit-key -> delta (bitwise identical on every thread)
      const long long db = (long long)((kW & 0x8000000000000000ull)
                                           ? (kW ^ 0x8000000000000000ull) : ~kW);
      D += __longlong_as_double(db);
      {
        const int c = j1 - 1;
        if (tid == ((c & 255) | ((c >> 10) << 8)))
          usedMask |= 1u << ((c >> 8) & 3);
      }
      if (tid == s) recCol = j1;
      const int pj1 = (int)p[j1];   // off-path (dead value on final step)
      j1v = j1;
      ++s;
      if (cdtx < 0.0f) { S = s; break; }   // free column => path complete
      ui0 = cdun; tX = cdtx; tY = cdty; i0 = pj1;
    }

    // ---- row tail: NO barrier E (R15 proof carries over) ----
    nxtT = rowTgt[i < T ? i + 1 : T];
    if (S == 1) {
      // fast path: owner writes its own colDat + p (owner-only pre-barrier
      // reader; p read by others only post-next-barrier). unew = D bitwise.
      const int c = j1v - 1;
      if (tid == ((c & 255) | ((c >> 10) << 8))) {
        p[j1v] = (short)i;
        CD c2; c2.u = D; c2.tx = tX; c2.ty = tY;
        colDat[j1v] = c2;
      }
    } else {
      const double Dfin = D;
      if (tid < S) {
        p[recCol] = (short)recRow;                  // augment
        const double unew = recU + (Dfin - recD);
        CD c2; c2.u = unew; c2.tx = recTX; c2.ty = recTY;
        colDat[recCol] = c2;
        if (tid >= 1) {
          vdelta[recPrev - 1] = Dfin - recD;        // path cols distinct
        }
      }
      __syncthreads();              // F: scatter visible
#pragma unroll
      for (int k = 0; k < KPT; ++k) {
        const int a = base + ((half * 4 + k) << 8);
        const double dv = vdelta[a];
        vreg[k] -= dv;              // 0.0 slots are bitwise no-ops
        vdelta[a] = 0.0;
      }
    }
  }
  __syncthreads();

  // ---- extract assignment, rank-sort (distinct values), write int32 ----
  for (int j = 1 + tid; j <= Q; j += NT) {
    const int pi = (int)p[j];
    if (pi > 0) ansArr[pi - 1] = j - 1;
  }
  __syncthreads();
  if (tid < T) {
    const int a = ansArr[tid];
    int rank = 0;
    for (int t2 = 0; t2 < T; ++t2) rank += (ansArr[t2] < a) ? 1 : 0;
    out[(size_t)b * T + rank] = a;                      // row_ind
    out[(size_t)B * T + (size_t)b * T + rank] = tid;    // col_ind
  }
}

extern "C" void kernel_launch(void* const* d_in, const int* in_sizes, int n_in,
                              void* d_out, int out_size, void* d_ws, size_t ws_size,
                              hipStream_t stream) {
  const float* outs = (const float*)d_in[0];   // (8, 2048, 3) fp32
  const float* tgts = (const float*)d_in[1];   // (8, 256, 3) fp32
  int* out = (int*)d_out;                      // row_ind (8,256) ++ col_ind (8,256)
  hungarian_r18<<<B, NT, 0, stream>>>(outs, tgts, out);
}